// Round 1
// baseline (1649.658 us; speedup 1.0000x reference)
//
#include <hip/hip_runtime.h>
#include <hip/hip_bf16.h>
#include <cfloat>

#define CH   1024
#define HW   4096
#define NSVD 500
#define TFR  3
#define SREF 2

// ---------------------------------------------------------------------------
// ws layout (floats):
//   fn/fd   : 0            .. 12,582,912   (3*1024*4096)
//   invn    : 12,582,912   (3*4096)
//   counts  : 12,595,200   (pad 64)
//   protos  : 12,595,264   (2*1024)
//   proto   : 12,597,312   (1024)
//   pmax    : 12,598,336   (2*4*4096)
//   pidx    : 12,631,104   (2*4*4096, as int)
//   total ~ 50.7 MB
// coef (3*500*4096 floats) lives in d_out's sim region (dead before sim GEMM).
// ---------------------------------------------------------------------------

// Column L2 norms over C for layout (t, c, n): invn[t*HW+n] = 1/max(||.||,1e-12)
__global__ __launch_bounds__(256) void colnorm_k(const float* __restrict__ src,
                                                 float* __restrict__ invn) {
  int blk = blockIdx.x;              // t*64 + n-chunk
  int t = blk >> 6;
  int n0 = (blk & 63) * 64;
  int tid = threadIdx.x;
  int nl = tid & 63, r = tid >> 6;
  const float* base = src + (size_t)t * CH * HW + n0 + nl;
  float s = 0.f;
  for (int c = r; c < CH; c += 4) {
    float v = base[(size_t)c * HW];
    s += v * v;
  }
  __shared__ float red[256];
  red[tid] = s;
  __syncthreads();
  if (r == 0) {
    float tot = red[nl] + red[nl + 64] + red[nl + 128] + red[nl + 192];
    invn[t * HW + n0 + nl] = 1.0f / fmaxf(sqrtf(tot), 1e-12f);
  }
}

// dst[t,c,n] = src[t,c,n] * invn[t,n]   (float4, in-place safe)
__global__ __launch_bounds__(256) void scale_k(const float* __restrict__ src,
                                               const float* __restrict__ invn,
                                               float* __restrict__ dst) {
  size_t i = ((size_t)blockIdx.x * 256 + threadIdx.x) * 4;
  int t = (int)(i / ((size_t)CH * HW));
  int n = (int)(i & (HW - 1));
  float4 v = *reinterpret_cast<const float4*>(src + i);
  float4 w = *reinterpret_cast<const float4*>(invn + t * HW + n);
  v.x *= w.x; v.y *= w.y; v.z *= w.z; v.w *= w.w;
  *reinterpret_cast<float4*>(dst + i) = v;
}

// C[m,n] = sum_k A[k*lda+m] * B[k*ldb+n]   (TN GEMM, batched over z)
__global__ __launch_bounds__(256) void gemm_tn_k(
    const float* __restrict__ A, int lda, size_t sA,
    const float* __restrict__ B, int ldb, size_t sB,
    float* __restrict__ C, int ldc, size_t sC,
    int M, int N, int K) {
  A += (size_t)blockIdx.z * sA;
  B += (size_t)blockIdx.z * sB;
  C += (size_t)blockIdx.z * sC;
  int m0 = blockIdx.x * 64, n0 = blockIdx.y * 64;
  int tid = threadIdx.x;
  int tx = tid & 15, ty = tid >> 4;
  int lm = tid & 63, lk = tid >> 6;
  __shared__ float As[16][64];
  __shared__ float Bs[16][64];
  float acc[4][4] = {};
  for (int k0 = 0; k0 < K; k0 += 16) {
#pragma unroll
    for (int i = 0; i < 4; i++) {
      int k = k0 + lk + i * 4;
      int m = m0 + lm;
      As[lk + i * 4][lm] = (k < K && m < M) ? A[(size_t)k * lda + m] : 0.f;
      int n = n0 + lm;
      Bs[lk + i * 4][lm] = (k < K && n < N) ? B[(size_t)k * ldb + n] : 0.f;
    }
    __syncthreads();
#pragma unroll
    for (int kk = 0; kk < 16; kk++) {
      float a[4], b[4];
#pragma unroll
      for (int i = 0; i < 4; i++) a[i] = As[kk][ty * 4 + i];
#pragma unroll
      for (int j = 0; j < 4; j++) b[j] = Bs[kk][tx * 4 + j];
#pragma unroll
      for (int i = 0; i < 4; i++)
#pragma unroll
        for (int j = 0; j < 4; j++) acc[i][j] += a[i] * b[j];
    }
    __syncthreads();
  }
#pragma unroll
  for (int i = 0; i < 4; i++) {
    int m = m0 + ty * 4 + i;
    if (m >= M) continue;
#pragma unroll
    for (int j = 0; j < 4; j++) {
      int n = n0 + tx * 4 + j;
      if (n < N) C[(size_t)m * ldc + n] = acc[i][j];
    }
  }
}

// fn[t,m,n] -= sum_k basis[m*NSVD+k] * coef[t,k,n]   (NN GEMM, fused residual)
__global__ __launch_bounds__(256) void gemm_nn_resid_k(
    const float* __restrict__ A /*basis*/, const float* __restrict__ Bc /*coef*/,
    float* __restrict__ FN) {
  int t = blockIdx.z;
  const float* B = Bc + (size_t)t * NSVD * HW;
  float* C = FN + (size_t)t * CH * HW;
  int m0 = blockIdx.x * 64, n0 = blockIdx.y * 64;
  int tid = threadIdx.x;
  int tx = tid & 15, ty = tid >> 4;
  int lm = tid & 63, lk = tid >> 6;
  int am = tid >> 2, ak = (tid & 3) * 4;
  __shared__ float As[16][64];
  __shared__ float Bs[16][64];
  float acc[4][4] = {};
  for (int k0 = 0; k0 < NSVD; k0 += 16) {
#pragma unroll
    for (int i = 0; i < 4; i++) {
      int k = k0 + ak + i;
      As[ak + i][am] = (k < NSVD) ? A[(size_t)(m0 + am) * NSVD + k] : 0.f;
    }
#pragma unroll
    for (int i = 0; i < 4; i++) {
      int k = k0 + lk + i * 4;
      Bs[lk + i * 4][lm] = (k < NSVD) ? B[(size_t)k * HW + n0 + lm] : 0.f;
    }
    __syncthreads();
#pragma unroll
    for (int kk = 0; kk < 16; kk++) {
      float a[4], b[4];
#pragma unroll
      for (int i = 0; i < 4; i++) a[i] = As[kk][ty * 4 + i];
#pragma unroll
      for (int j = 0; j < 4; j++) b[j] = Bs[kk][tx * 4 + j];
#pragma unroll
      for (int i = 0; i < 4; i++)
#pragma unroll
        for (int j = 0; j < 4; j++) acc[i][j] += a[i] * b[j];
    }
    __syncthreads();
  }
#pragma unroll
  for (int i = 0; i < 4; i++) {
    size_t off = (size_t)(m0 + ty * 4 + i) * HW + n0 + tx * 4;
#pragma unroll
    for (int j = 0; j < 4; j++) {
      float v = C[off + j];
      C[off + j] = v - acc[i][j];
    }
  }
}

__global__ __launch_bounds__(256) void count_k(const int* __restrict__ mask,
                                               float* __restrict__ counts) {
  int s = blockIdx.x;
  int tid = threadIdx.x;
  int c = 0;
  for (int i = tid; i < HW; i += 256) c += (mask[s * HW + i] != 0);
  __shared__ int red[256];
  red[tid] = c;
  __syncthreads();
  for (int o = 128; o > 0; o >>= 1) {
    if (tid < o) red[tid] += red[tid + o];
    __syncthreads();
  }
  if (tid == 0) counts[s] = fmaxf((float)red[0], 1.0f);
}

__global__ __launch_bounds__(256) void proto_k(const float* __restrict__ fd,
                                               const int* __restrict__ mask,
                                               const float* __restrict__ counts,
                                               float* __restrict__ protos) {
  int s = blockIdx.x >> 10, c = blockIdx.x & 1023;
  int tid = threadIdx.x;
  const float* row = fd + ((size_t)s * CH + c) * HW;
  const int* mrow = mask + s * HW;
  float acc = 0.f;
  for (int i = tid; i < HW; i += 256) acc += mrow[i] ? row[i] : 0.f;
  __shared__ float red[256];
  red[tid] = acc;
  __syncthreads();
  for (int o = 128; o > 0; o >>= 1) {
    if (tid < o) red[tid] += red[tid + o];
    __syncthreads();
  }
  if (tid == 0) protos[blockIdx.x] = red[0] / counts[s];
}

__global__ __launch_bounds__(256) void protonorm_k(const float* __restrict__ protos,
                                                   float* __restrict__ proto) {
  int tid = threadIdx.x;
  __shared__ float sm[CH];
  __shared__ float red[256];
  float ss = 0.f;
  for (int c = tid; c < CH; c += 256) {
    float m = 0.5f * (protos[c] + protos[CH + c]);
    sm[c] = m;
    ss += m * m;
  }
  red[tid] = ss;
  __syncthreads();
  for (int o = 128; o > 0; o >>= 1) {
    if (tid < o) red[tid] += red[tid + o];
    __syncthreads();
  }
  __syncthreads();
  float inv = 1.0f / fmaxf(sqrtf(red[0]), 1e-12f);
  for (int c = tid; c < CH; c += 256) proto[c] = sm[c] * inv;
}

__global__ __launch_bounds__(256) void simfwd_k(const float* __restrict__ fd,
                                                const float* __restrict__ proto,
                                                float* __restrict__ out) {
  __shared__ float p[CH];
  for (int c = threadIdx.x; c < CH; c += 256) p[c] = proto[c];
  __syncthreads();
  int n = blockIdx.x * 256 + threadIdx.x;
  const float* tgt = fd + (size_t)2 * CH * HW + n;
  float s = 0.f;
  for (int c = 0; c < CH; c++) s += tgt[(size_t)c * HW] * p[c];
  out[n] = s;
}

// Partial argmax over hw chunks of 1024; first-occurrence tie-break.
__global__ __launch_bounds__(256) void argmax_part_k(const float* __restrict__ sim,
                                                     float* __restrict__ pmax,
                                                     int* __restrict__ pidx) {
  int s = blockIdx.z, hwc = blockIdx.y, xy0 = blockIdx.x * 64;
  int tid = threadIdx.x, xl = tid & 63, r = tid >> 6;
  const float* base = sim + ((size_t)s * HW + hwc * 1024) * HW + xy0 + xl;
  float bv = -FLT_MAX;
  int bi = 0x7fffffff;
  for (int t = 0; t < 256; t++) {
    int hw = r + 4 * t;                       // ascending within this thread
    float v = base[(size_t)hw * HW];
    if (v > bv) { bv = v; bi = hwc * 1024 + hw; }
  }
  __shared__ float sv[256];
  __shared__ int si[256];
  sv[tid] = bv;
  si[tid] = bi;
  __syncthreads();
  if (r == 0) {
    for (int rr = 1; rr < 4; rr++) {
      float v = sv[tid + 64 * rr];
      int i = si[tid + 64 * rr];
      if (v > bv || (v == bv && i < bi)) { bv = v; bi = i; }
    }
    int o = (s * 4 + hwc) * HW + xy0 + xl;
    pmax[o] = bv;
    pidx[o] = bi;
  }
}

__global__ __launch_bounds__(256) void votes_k(const float* __restrict__ pmax,
                                               const int* __restrict__ pidx,
                                               const int* __restrict__ mask,
                                               float* __restrict__ out) {
  int xy = blockIdx.x * 256 + threadIdx.x;
  int vote = 0;
  for (int s = 0; s < SREF; s++) {
    float bv = -FLT_MAX;
    int bi = 0x7fffffff;
    for (int hwc = 0; hwc < 4; hwc++) {
      int o = (s * 4 + hwc) * HW + xy;
      float v = pmax[o];
      int i = pidx[o];
      if (v > bv || (v == bv && i < bi)) { bv = v; bi = i; }
    }
    vote += (mask[s * HW + bi] != 0);
  }
  out[xy] = (float)vote;
}

extern "C" void kernel_launch(void* const* d_in, const int* in_sizes, int n_in,
                              void* d_out, int out_size, void* d_ws, size_t ws_size,
                              hipStream_t stream) {
  const float* fmaps = (const float*)d_in[0];
  const int* mask = (const int*)d_in[1];
  const float* basis = (const float*)d_in[2];
  float* out = (float*)d_out;
  float* ws = (float*)d_ws;

  float* fn = ws;                         // 12,582,912 floats (fn, then fd in-place)
  float* invn = ws + 12582912;
  float* counts = ws + 12595200;
  float* protos = ws + 12595264;
  float* proto = ws + 12597312;
  float* pmax = ws + 12598336;
  int* pidx = (int*)(ws + 12631104);

  float* coef = out;                      // scratch inside sim region (dead before sim GEMM)
  float* sim = out;
  float* simfwd = out + 33554432;
  float* votes = out + 33558528;

  // 1) fn = l2norm(fmaps, axis=C)
  colnorm_k<<<dim3(TFR * HW / 64), 256, 0, stream>>>(fmaps, invn);
  scale_k<<<dim3(TFR * CH * HW / 1024), 256, 0, stream>>>(fmaps, invn, fn);

  // 2) coef = basis^T @ fn   (M=500, N=4096, K=1024, batch 3)
  gemm_tn_k<<<dim3(8, 64, 3), 256, 0, stream>>>(
      basis, NSVD, 0, fn, HW, (size_t)CH * HW, coef, HW, (size_t)NSVD * HW,
      NSVD, HW, CH);

  // 3) fd_pre = fn - basis @ coef (in-place), then re-normalize
  gemm_nn_resid_k<<<dim3(16, 64, 3), 256, 0, stream>>>(basis, coef, fn);
  colnorm_k<<<dim3(TFR * HW / 64), 256, 0, stream>>>(fn, invn);
  scale_k<<<dim3(TFR * CH * HW / 1024), 256, 0, stream>>>(fn, invn, fn);

  // 4) prototype
  count_k<<<2, 256, 0, stream>>>(mask, counts);
  proto_k<<<2048, 256, 0, stream>>>(fn, mask, counts, protos);
  protonorm_k<<<1, 256, 0, stream>>>(protos, proto);

  // 5) sim_fwd
  simfwd_k<<<16, 256, 0, stream>>>(fn, proto, simfwd);

  // 6) sim = fd_refs^T @ fd_tgt  (M=4096 per s, N=4096, K=1024)
  gemm_tn_k<<<dim3(64, 64, 2), 256, 0, stream>>>(
      fn, HW, (size_t)CH * HW, fn + (size_t)2 * CH * HW, HW, 0, sim, HW,
      (size_t)HW * HW, HW, HW, CH);

  // 7) votes
  argmax_part_k<<<dim3(64, 4, 2), 256, 0, stream>>>(sim, pmax, pidx);
  votes_k<<<16, 256, 0, stream>>>(pmax, pidx, mask, votes);
}

// Round 2
// 914.089 us; speedup vs baseline: 1.8047x; 1.8047x over previous
//
#include <hip/hip_runtime.h>
#include <hip/hip_bf16.h>
#include <cfloat>

#define CH   1024
#define HW   4096
#define NSVD 500
#define TFR  3
#define SREF 2

typedef __attribute__((ext_vector_type(4))) float f32x4;
typedef __attribute__((ext_vector_type(4))) unsigned int u32x4;
typedef __attribute__((ext_vector_type(8))) short short8;

// ---------------------------------------------------------------------------
// ws layout (floats):
//   fn/fd   : 0            .. 12,582,912   (3*1024*4096)  fp32, then packed u32
//   invn    : 12,582,912   (3*4096)
//   counts  : 12,595,200   (pad 64)
//   protos  : 12,595,264   (2*1024)
//   proto   : 12,597,312   (1024)
//   pmax    : 12,598,336   (2*4*4096)
//   pidx    : 12,631,104   (2*4*4096, as int)
// coef (3*500*4096 floats) lives in d_out's sim region (dead before sim GEMM).
// ---------------------------------------------------------------------------

__device__ inline unsigned bfr(float x) {        // fp32 -> bf16 bits, RNE
  unsigned u = __float_as_uint(x);
  return (u + 0x7fffu + ((u >> 16) & 1u)) >> 16;
}
__device__ inline unsigned packhl(float x) {     // (bf16 hi << 16) | bf16(residual)
  unsigned h = bfr(x);
  float lo = x - __uint_as_float(h << 16);
  unsigned l = bfr(lo);
  return (h << 16) | l;
}
__device__ inline float unpackhl(unsigned p) {
  return __uint_as_float(p & 0xFFFF0000u) + __uint_as_float(p << 16);
}

// Column L2 norms over C for layout (t, c, n): invn[t*HW+n] = 1/max(||.||,1e-12)
__global__ __launch_bounds__(256) void colnorm_k(const float* __restrict__ src,
                                                 float* __restrict__ invn) {
  int blk = blockIdx.x;
  int t = blk >> 6;
  int n0 = (blk & 63) * 64;
  int tid = threadIdx.x;
  int nl = tid & 63, r = tid >> 6;
  const float* base = src + (size_t)t * CH * HW + n0 + nl;
  float s = 0.f;
  for (int c = r; c < CH; c += 4) {
    float v = base[(size_t)c * HW];
    s += v * v;
  }
  __shared__ float red[256];
  red[tid] = s;
  __syncthreads();
  if (r == 0) {
    float tot = red[nl] + red[nl + 64] + red[nl + 128] + red[nl + 192];
    invn[t * HW + n0 + nl] = 1.0f / fmaxf(sqrtf(tot), 1e-12f);
  }
}

// dst[t,c,n] = src[t,c,n] * invn[t,n]   (float4)
__global__ __launch_bounds__(256) void scale_k(const float* __restrict__ src,
                                               const float* __restrict__ invn,
                                               float* __restrict__ dst) {
  size_t i = ((size_t)blockIdx.x * 256 + threadIdx.x) * 4;
  int t = (int)(i / ((size_t)CH * HW));
  int n = (int)(i & (HW - 1));
  float4 v = *reinterpret_cast<const float4*>(src + i);
  float4 w = *reinterpret_cast<const float4*>(invn + t * HW + n);
  v.x *= w.x; v.y *= w.y; v.z *= w.z; v.w *= w.w;
  *reinterpret_cast<float4*>(dst + i) = v;
}

// dst[t,c,n] = pack_hi_lo(src[t,c,n] * invn[t,n])   — in-place safe
__global__ __launch_bounds__(256) void scale_pack_k(const float* __restrict__ src,
                                                    const float* __restrict__ invn,
                                                    unsigned* __restrict__ dst) {
  size_t i = ((size_t)blockIdx.x * 256 + threadIdx.x) * 4;
  int t = (int)(i / ((size_t)CH * HW));
  int n = (int)(i & (HW - 1));
  float4 v = *reinterpret_cast<const float4*>(src + i);
  float4 w = *reinterpret_cast<const float4*>(invn + t * HW + n);
  u32x4 o;
  o.x = packhl(v.x * w.x);
  o.y = packhl(v.y * w.y);
  o.z = packhl(v.z * w.z);
  o.w = packhl(v.w * w.w);
  *reinterpret_cast<u32x4*>(dst + i) = o;
}

// C[m,n] = sum_k A[k*lda+m] * B[k*ldb+n]   (TN GEMM, batched; coef only now)
__global__ __launch_bounds__(256) void gemm_tn_k(
    const float* __restrict__ A, int lda, size_t sA,
    const float* __restrict__ B, int ldb, size_t sB,
    float* __restrict__ C, int ldc, size_t sC,
    int M, int N, int K) {
  A += (size_t)blockIdx.z * sA;
  B += (size_t)blockIdx.z * sB;
  C += (size_t)blockIdx.z * sC;
  int m0 = blockIdx.x * 64, n0 = blockIdx.y * 64;
  int tid = threadIdx.x;
  int tx = tid & 15, ty = tid >> 4;
  int lm = tid & 63, lk = tid >> 6;
  __shared__ float As[16][64];
  __shared__ float Bs[16][64];
  float acc[4][4] = {};
  for (int k0 = 0; k0 < K; k0 += 16) {
#pragma unroll
    for (int i = 0; i < 4; i++) {
      int k = k0 + lk + i * 4;
      int m = m0 + lm;
      As[lk + i * 4][lm] = (k < K && m < M) ? A[(size_t)k * lda + m] : 0.f;
      int n = n0 + lm;
      Bs[lk + i * 4][lm] = (k < K && n < N) ? B[(size_t)k * ldb + n] : 0.f;
    }
    __syncthreads();
#pragma unroll
    for (int kk = 0; kk < 16; kk++) {
      float a[4], b[4];
#pragma unroll
      for (int i = 0; i < 4; i++) a[i] = As[kk][ty * 4 + i];
#pragma unroll
      for (int j = 0; j < 4; j++) b[j] = Bs[kk][tx * 4 + j];
#pragma unroll
      for (int i = 0; i < 4; i++)
#pragma unroll
        for (int j = 0; j < 4; j++) acc[i][j] += a[i] * b[j];
    }
    __syncthreads();
  }
#pragma unroll
  for (int i = 0; i < 4; i++) {
    int m = m0 + ty * 4 + i;
    if (m >= M) continue;
#pragma unroll
    for (int j = 0; j < 4; j++) {
      int n = n0 + tx * 4 + j;
      if (n < N) C[(size_t)m * ldc + n] = acc[i][j];
    }
  }
}

// fn[t,m,n] -= sum_k basis[m*NSVD+k] * coef[t,k,n]
__global__ __launch_bounds__(256) void gemm_nn_resid_k(
    const float* __restrict__ A, const float* __restrict__ Bc,
    float* __restrict__ FN) {
  int t = blockIdx.z;
  const float* B = Bc + (size_t)t * NSVD * HW;
  float* C = FN + (size_t)t * CH * HW;
  int m0 = blockIdx.x * 64, n0 = blockIdx.y * 64;
  int tid = threadIdx.x;
  int tx = tid & 15, ty = tid >> 4;
  int lm = tid & 63, lk = tid >> 6;
  int am = tid >> 2, ak = (tid & 3) * 4;
  __shared__ float As[16][64];
  __shared__ float Bs[16][64];
  float acc[4][4] = {};
  for (int k0 = 0; k0 < NSVD; k0 += 16) {
#pragma unroll
    for (int i = 0; i < 4; i++) {
      int k = k0 + ak + i;
      As[ak + i][am] = (k < NSVD) ? A[(size_t)(m0 + am) * NSVD + k] : 0.f;
    }
#pragma unroll
    for (int i = 0; i < 4; i++) {
      int k = k0 + lk + i * 4;
      Bs[lk + i * 4][lm] = (k < NSVD) ? B[(size_t)k * HW + n0 + lm] : 0.f;
    }
    __syncthreads();
#pragma unroll
    for (int kk = 0; kk < 16; kk++) {
      float a[4], b[4];
#pragma unroll
      for (int i = 0; i < 4; i++) a[i] = As[kk][ty * 4 + i];
#pragma unroll
      for (int j = 0; j < 4; j++) b[j] = Bs[kk][tx * 4 + j];
#pragma unroll
      for (int i = 0; i < 4; i++)
#pragma unroll
        for (int j = 0; j < 4; j++) acc[i][j] += a[i] * b[j];
    }
    __syncthreads();
  }
#pragma unroll
  for (int i = 0; i < 4; i++) {
    size_t off = (size_t)(m0 + ty * 4 + i) * HW + n0 + tx * 4;
#pragma unroll
    for (int j = 0; j < 4; j++) {
      float v = C[off + j];
      C[off + j] = v - acc[i][j];
    }
  }
}

__global__ __launch_bounds__(256) void count_k(const int* __restrict__ mask,
                                               float* __restrict__ counts) {
  int s = blockIdx.x;
  int tid = threadIdx.x;
  int c = 0;
  for (int i = tid; i < HW; i += 256) c += (mask[s * HW + i] != 0);
  __shared__ int red[256];
  red[tid] = c;
  __syncthreads();
  for (int o = 128; o > 0; o >>= 1) {
    if (tid < o) red[tid] += red[tid + o];
    __syncthreads();
  }
  if (tid == 0) counts[s] = fmaxf((float)red[0], 1.0f);
}

// reads packed hi/lo fd
__global__ __launch_bounds__(256) void proto_k(const unsigned* __restrict__ fd,
                                               const int* __restrict__ mask,
                                               const float* __restrict__ counts,
                                               float* __restrict__ protos) {
  int s = blockIdx.x >> 10, c = blockIdx.x & 1023;
  int tid = threadIdx.x;
  const unsigned* row = fd + ((size_t)s * CH + c) * HW;
  const int* mrow = mask + s * HW;
  float acc = 0.f;
  for (int i = tid; i < HW; i += 256) acc += mrow[i] ? unpackhl(row[i]) : 0.f;
  __shared__ float red[256];
  red[tid] = acc;
  __syncthreads();
  for (int o = 128; o > 0; o >>= 1) {
    if (tid < o) red[tid] += red[tid + o];
    __syncthreads();
  }
  if (tid == 0) protos[blockIdx.x] = red[0] / counts[s];
}

__global__ __launch_bounds__(256) void protonorm_k(const float* __restrict__ protos,
                                                   float* __restrict__ proto) {
  int tid = threadIdx.x;
  __shared__ float sm[CH];
  __shared__ float red[256];
  float ss = 0.f;
  for (int c = tid; c < CH; c += 256) {
    float m = 0.5f * (protos[c] + protos[CH + c]);
    sm[c] = m;
    ss += m * m;
  }
  red[tid] = ss;
  __syncthreads();
  for (int o = 128; o > 0; o >>= 1) {
    if (tid < o) red[tid] += red[tid + o];
    __syncthreads();
  }
  __syncthreads();
  float inv = 1.0f / fmaxf(sqrtf(red[0]), 1e-12f);
  for (int c = tid; c < CH; c += 256) proto[c] = sm[c] * inv;
}

__global__ __launch_bounds__(256) void simfwd_k(const unsigned* __restrict__ fd,
                                                const float* __restrict__ proto,
                                                float* __restrict__ out) {
  __shared__ float p[CH];
  for (int c = threadIdx.x; c < CH; c += 256) p[c] = proto[c];
  __syncthreads();
  int n = blockIdx.x * 256 + threadIdx.x;
  const unsigned* tgt = fd + (size_t)2 * CH * HW + n;
  float s = 0.f;
  for (int c = 0; c < CH; c++) s += unpackhl(tgt[(size_t)c * HW]) * p[c];
  out[n] = s;
}

// ---------------------------------------------------------------------------
// sim = fd_refs^T @ fd_tgt via split-bf16 MFMA (hi*hi + hi*lo + lo*hi).
// Inputs packed u32 = (bf16hi<<16)|bf16lo, layout [t][k=c][n=xy].
// 128x128 tile, BK=32, 4 waves, each wave a 64x64 quadrant of 4x4 16x16 frags.
// LDS: [m][k] packed u32, XOR-swizzled in 16B blocks (kb ^= m&7).
// ---------------------------------------------------------------------------
#define BM 128
#define BK 32

__global__ __launch_bounds__(256) void sim_mfma_k(const unsigned* __restrict__ P,
                                                  float* __restrict__ C) {
  int s = blockIdx.z;
  int m0 = blockIdx.x * BM, n0 = blockIdx.y * BM;
  const unsigned* Ag = P + (size_t)s * CH * HW;
  const unsigned* Bg = P + (size_t)2 * CH * HW;
  float* Cout = C + (size_t)s * HW * HW;

  __shared__ unsigned As[BM * BK];   // 16 KB
  __shared__ unsigned Bs[BM * BK];   // 16 KB

  int tid = threadIdx.x;
  int lane = tid & 63, wave = tid >> 6;
  int wr = wave >> 1, wc = wave & 1;

  int sm = tid & 127;          // staged m (or n) row
  int skh = tid >> 7;          // k-half 0/1

  int fcol = lane & 15;        // fragment m/n index
  int fkb = (lane >> 4) * 2;   // fragment kb base (16B blocks of 4 u32)

  f32x4 acc[4][4] = {};
  unsigned ra[16], rb[16];

#define LOADT(KT)                                                        \
  {                                                                      \
    const unsigned* pa = Ag + (size_t)((KT) * BK + skh * 16) * HW + m0 + sm; \
    const unsigned* pb = Bg + (size_t)((KT) * BK + skh * 16) * HW + n0 + sm; \
    _Pragma("unroll")                                                    \
    for (int i = 0; i < 16; i++) {                                       \
      ra[i] = pa[(size_t)i * HW];                                        \
      rb[i] = pb[(size_t)i * HW];                                        \
    }                                                                    \
  }

  LOADT(0);

  for (int kt = 0; kt < CH / BK; ++kt) {
    __syncthreads();   // previous iteration's LDS reads complete
#pragma unroll
    for (int b = 0; b < 4; b++) {
      int kbs = ((skh * 4 + b) ^ (sm & 7)) * 4;
      u32x4 wa = {ra[b * 4 + 0], ra[b * 4 + 1], ra[b * 4 + 2], ra[b * 4 + 3]};
      u32x4 wb = {rb[b * 4 + 0], rb[b * 4 + 1], rb[b * 4 + 2], rb[b * 4 + 3]};
      *reinterpret_cast<u32x4*>(&As[sm * BK + kbs]) = wa;
      *reinterpret_cast<u32x4*>(&Bs[sm * BK + kbs]) = wb;
    }
    __syncthreads();

    if (kt + 1 < CH / BK) LOADT(kt + 1);   // prefetch hides under MFMA

    // B fragments (hi/lo) for all 4 n-frags
    short8 bh[4], bl[4];
#pragma unroll
    for (int nf = 0; nf < 4; nf++) {
      int nloc = wc * 64 + nf * 16 + fcol;
      const unsigned* rowp = &Bs[nloc * BK];
      u32x4 p0 = *reinterpret_cast<const u32x4*>(&rowp[((fkb) ^ (nloc & 7)) * 4]);
      u32x4 p1 = *reinterpret_cast<const u32x4*>(&rowp[((fkb + 1) ^ (nloc & 7)) * 4]);
      u32x4 h, l;
      h.x = __builtin_amdgcn_perm(p0.y, p0.x, 0x07060302u);
      h.y = __builtin_amdgcn_perm(p0.w, p0.z, 0x07060302u);
      h.z = __builtin_amdgcn_perm(p1.y, p1.x, 0x07060302u);
      h.w = __builtin_amdgcn_perm(p1.w, p1.z, 0x07060302u);
      l.x = __builtin_amdgcn_perm(p0.y, p0.x, 0x05040100u);
      l.y = __builtin_amdgcn_perm(p0.w, p0.z, 0x05040100u);
      l.z = __builtin_amdgcn_perm(p1.y, p1.x, 0x05040100u);
      l.w = __builtin_amdgcn_perm(p1.w, p1.z, 0x05040100u);
      bh[nf] = __builtin_bit_cast(short8, h);
      bl[nf] = __builtin_bit_cast(short8, l);
    }
#pragma unroll
    for (int mf = 0; mf < 4; mf++) {
      int mloc = wr * 64 + mf * 16 + fcol;
      const unsigned* rowp = &As[mloc * BK];
      u32x4 p0 = *reinterpret_cast<const u32x4*>(&rowp[((fkb) ^ (mloc & 7)) * 4]);
      u32x4 p1 = *reinterpret_cast<const u32x4*>(&rowp[((fkb + 1) ^ (mloc & 7)) * 4]);
      u32x4 h, l;
      h.x = __builtin_amdgcn_perm(p0.y, p0.x, 0x07060302u);
      h.y = __builtin_amdgcn_perm(p0.w, p0.z, 0x07060302u);
      h.z = __builtin_amdgcn_perm(p1.y, p1.x, 0x07060302u);
      h.w = __builtin_amdgcn_perm(p1.w, p1.z, 0x07060302u);
      l.x = __builtin_amdgcn_perm(p0.y, p0.x, 0x05040100u);
      l.y = __builtin_amdgcn_perm(p0.w, p0.z, 0x05040100u);
      l.z = __builtin_amdgcn_perm(p1.y, p1.x, 0x05040100u);
      l.w = __builtin_amdgcn_perm(p1.w, p1.z, 0x05040100u);
      short8 ah = __builtin_bit_cast(short8, h);
      short8 al = __builtin_bit_cast(short8, l);
#pragma unroll
      for (int nf = 0; nf < 4; nf++) {
        acc[mf][nf] = __builtin_amdgcn_mfma_f32_16x16x32_bf16(ah, bh[nf], acc[mf][nf], 0, 0, 0);
        acc[mf][nf] = __builtin_amdgcn_mfma_f32_16x16x32_bf16(ah, bl[nf], acc[mf][nf], 0, 0, 0);
        acc[mf][nf] = __builtin_amdgcn_mfma_f32_16x16x32_bf16(al, bh[nf], acc[mf][nf], 0, 0, 0);
      }
    }
  }
#undef LOADT

  int rbase = (lane >> 4) * 4;
#pragma unroll
  for (int mf = 0; mf < 4; mf++) {
    int m = m0 + wr * 64 + mf * 16 + rbase;
#pragma unroll
    for (int nf = 0; nf < 4; nf++) {
      int n = n0 + wc * 64 + nf * 16 + fcol;
#pragma unroll
      for (int r = 0; r < 4; r++) {
        Cout[(size_t)(m + r) * HW + n] = acc[mf][nf][r];
      }
    }
  }
}

// Partial argmax over hw chunks of 1024; first-occurrence tie-break.
__global__ __launch_bounds__(256) void argmax_part_k(const float* __restrict__ sim,
                                                     float* __restrict__ pmax,
                                                     int* __restrict__ pidx) {
  int s = blockIdx.z, hwc = blockIdx.y, xy0 = blockIdx.x * 64;
  int tid = threadIdx.x, xl = tid & 63, r = tid >> 6;
  const float* base = sim + ((size_t)s * HW + hwc * 1024) * HW + xy0 + xl;
  float bv = -FLT_MAX;
  int bi = 0x7fffffff;
  for (int t = 0; t < 256; t++) {
    int hw = r + 4 * t;
    float v = base[(size_t)hw * HW];
    if (v > bv) { bv = v; bi = hwc * 1024 + hw; }
  }
  __shared__ float sv[256];
  __shared__ int si[256];
  sv[tid] = bv;
  si[tid] = bi;
  __syncthreads();
  if (r == 0) {
    for (int rr = 1; rr < 4; rr++) {
      float v = sv[tid + 64 * rr];
      int i = si[tid + 64 * rr];
      if (v > bv || (v == bv && i < bi)) { bv = v; bi = i; }
    }
    int o = (s * 4 + hwc) * HW + xy0 + xl;
    pmax[o] = bv;
    pidx[o] = bi;
  }
}

__global__ __launch_bounds__(256) void votes_k(const float* __restrict__ pmax,
                                               const int* __restrict__ pidx,
                                               const int* __restrict__ mask,
                                               float* __restrict__ out) {
  int xy = blockIdx.x * 256 + threadIdx.x;
  int vote = 0;
  for (int s = 0; s < SREF; s++) {
    float bv = -FLT_MAX;
    int bi = 0x7fffffff;
    for (int hwc = 0; hwc < 4; hwc++) {
      int o = (s * 4 + hwc) * HW + xy;
      float v = pmax[o];
      int i = pidx[o];
      if (v > bv || (v == bv && i < bi)) { bv = v; bi = i; }
    }
    vote += (mask[s * HW + bi] != 0);
  }
  out[xy] = (float)vote;
}

extern "C" void kernel_launch(void* const* d_in, const int* in_sizes, int n_in,
                              void* d_out, int out_size, void* d_ws, size_t ws_size,
                              hipStream_t stream) {
  const float* fmaps = (const float*)d_in[0];
  const int* mask = (const int*)d_in[1];
  const float* basis = (const float*)d_in[2];
  float* out = (float*)d_out;
  float* ws = (float*)d_ws;

  float* fn = ws;
  unsigned* fnp = (unsigned*)ws;          // packed hi/lo view after scale_pack
  float* invn = ws + 12582912;
  float* counts = ws + 12595200;
  float* protos = ws + 12595264;
  float* proto = ws + 12597312;
  float* pmax = ws + 12598336;
  int* pidx = (int*)(ws + 12631104);

  float* coef = out;                      // scratch inside sim region
  float* sim = out;
  float* simfwd = out + 33554432;
  float* votes = out + 33558528;

  // 1) fn = l2norm(fmaps, axis=C)
  colnorm_k<<<dim3(TFR * HW / 64), 256, 0, stream>>>(fmaps, invn);
  scale_k<<<dim3(TFR * CH * HW / 1024), 256, 0, stream>>>(fmaps, invn, fn);

  // 2) coef = basis^T @ fn
  gemm_tn_k<<<dim3(8, 64, 3), 256, 0, stream>>>(
      basis, NSVD, 0, fn, HW, (size_t)CH * HW, coef, HW, (size_t)NSVD * HW,
      NSVD, HW, CH);

  // 3) residual, then renormalize + pack to split-bf16
  gemm_nn_resid_k<<<dim3(16, 64, 3), 256, 0, stream>>>(basis, coef, fn);
  colnorm_k<<<dim3(TFR * HW / 64), 256, 0, stream>>>(fn, invn);
  scale_pack_k<<<dim3(TFR * CH * HW / 1024), 256, 0, stream>>>(fn, invn, fnp);

  // 4) prototype (packed reads)
  count_k<<<2, 256, 0, stream>>>(mask, counts);
  proto_k<<<2048, 256, 0, stream>>>(fnp, mask, counts, protos);
  protonorm_k<<<1, 256, 0, stream>>>(protos, proto);

  // 5) sim_fwd
  simfwd_k<<<16, 256, 0, stream>>>(fnp, proto, simfwd);

  // 6) sim via split-bf16 MFMA
  sim_mfma_k<<<dim3(HW / BM, HW / BM, SREF), 256, 0, stream>>>(fnp, sim);

  // 7) votes
  argmax_part_k<<<dim3(64, 4, 2), 256, 0, stream>>>(sim, pmax, pidx);
  votes_k<<<16, 256, 0, stream>>>(pmax, pidx, mask, votes);
}

// Round 3
// 642.766 us; speedup vs baseline: 2.5665x; 1.4221x over previous
//
#include <hip/hip_runtime.h>
#include <hip/hip_bf16.h>
#include <cfloat>

#define CH   1024
#define HW   4096
#define NSVD 500
#define TFR  3
#define SREF 2

typedef __attribute__((ext_vector_type(4))) float f32x4;
typedef __attribute__((ext_vector_type(4))) unsigned int u32x4;
typedef __attribute__((ext_vector_type(8))) short short8;

// ---------------------------------------------------------------------------
// ws layout (floats):
//   fnp     : 0            .. 12,582,912   packed u32 (bf16hi<<16 | bf16lo)
//   invn    : 12,582,912   (3*4096)
//   counts  : 12,595,200   (pad 64)
//   protos  : 12,595,264   (2*1024)
//   proto   : 12,597,312   (1024)
//   pmax    : 12,598,336   (2*4*4096)
//   pidx    : 12,631,104   (2*4*4096, as int)
// d_out scratch (dead before sim GEMM overwrites):
//   fd_pre  : out + 0           (3*1024*4096 fp32)
//   Pp      : out + 16,777,216  (1024*1024 packed u32)
// ---------------------------------------------------------------------------

__device__ inline unsigned bfr(float x) {        // fp32 -> bf16 bits, RNE
  unsigned u = __float_as_uint(x);
  return (u + 0x7fffu + ((u >> 16) & 1u)) >> 16;
}
__device__ inline unsigned packhl(float x) {     // (bf16 hi << 16) | bf16(residual)
  unsigned h = bfr(x);
  float lo = x - __uint_as_float(h << 16);
  unsigned l = bfr(lo);
  return (h << 16) | l;
}
__device__ inline float unpackhl(unsigned p) {
  return __uint_as_float(p & 0xFFFF0000u) + __uint_as_float(p << 16);
}

// Column L2 norms over C for layout (t, c, n): invn[t*HW+n] = 1/max(||.||,1e-12)
__global__ __launch_bounds__(256) void colnorm_k(const float* __restrict__ src,
                                                 float* __restrict__ invn) {
  int blk = blockIdx.x;
  int t = blk >> 6;
  int n0 = (blk & 63) * 64;
  int tid = threadIdx.x;
  int nl = tid & 63, r = tid >> 6;
  const float* base = src + (size_t)t * CH * HW + n0 + nl;
  float s = 0.f;
  for (int c = r; c < CH; c += 4) {
    float v = base[(size_t)c * HW];
    s += v * v;
  }
  __shared__ float red[256];
  red[tid] = s;
  __syncthreads();
  if (r == 0) {
    float tot = red[nl] + red[nl + 64] + red[nl + 128] + red[nl + 192];
    invn[t * HW + n0 + nl] = 1.0f / fmaxf(sqrtf(tot), 1e-12f);
  }
}

// dst[t,c,n] = pack_hi_lo(src[t,c,n] * invn[t,n])
__global__ __launch_bounds__(256) void scale_pack_k(const float* __restrict__ src,
                                                    const float* __restrict__ invn,
                                                    unsigned* __restrict__ dst) {
  size_t i = ((size_t)blockIdx.x * 256 + threadIdx.x) * 4;
  int t = (int)(i / ((size_t)CH * HW));
  int n = (int)(i & (HW - 1));
  float4 v = *reinterpret_cast<const float4*>(src + i);
  float4 w = *reinterpret_cast<const float4*>(invn + t * HW + n);
  u32x4 o;
  o.x = packhl(v.x * w.x);
  o.y = packhl(v.y * w.y);
  o.z = packhl(v.z * w.z);
  o.w = packhl(v.w * w.w);
  *reinterpret_cast<u32x4*>(dst + i) = o;
}

// Pp = pack(I - basis @ basis^T)   — 1024x1024, K=500 (padded to 512). Symmetric.
__global__ __launch_bounds__(256) void proj_pack_k(const float* __restrict__ bas,
                                                   unsigned* __restrict__ Pp) {
  int m0 = blockIdx.x * 64, n0 = blockIdx.y * 64;
  int tid = threadIdx.x;
  int tx = tid & 15, ty = tid >> 4;
  int lm = tid & 63, lk = tid >> 6;      // 64 rows x 4 k-slots
  __shared__ float As[16][64];
  __shared__ float Bs[16][64];
  float acc[4][4] = {};
  for (int k0 = 0; k0 < 512; k0 += 16) {
#pragma unroll
    for (int i = 0; i < 4; i++) {
      int k = k0 + lk * 4 + i;
      As[lk * 4 + i][lm] = (k < NSVD) ? bas[(size_t)(m0 + lm) * NSVD + k] : 0.f;
      Bs[lk * 4 + i][lm] = (k < NSVD) ? bas[(size_t)(n0 + lm) * NSVD + k] : 0.f;
    }
    __syncthreads();
#pragma unroll
    for (int kk = 0; kk < 16; kk++) {
      float a[4], b[4];
#pragma unroll
      for (int i = 0; i < 4; i++) a[i] = As[kk][ty * 4 + i];
#pragma unroll
      for (int j = 0; j < 4; j++) b[j] = Bs[kk][tx * 4 + j];
#pragma unroll
      for (int i = 0; i < 4; i++)
#pragma unroll
        for (int j = 0; j < 4; j++) acc[i][j] += a[i] * b[j];
    }
    __syncthreads();
  }
#pragma unroll
  for (int i = 0; i < 4; i++) {
    int m = m0 + ty * 4 + i;
#pragma unroll
    for (int j = 0; j < 4; j++) {
      int n = n0 + tx * 4 + j;
      float v = ((m == n) ? 1.0f : 0.0f) - acc[i][j];
      Pp[(size_t)m * CH + n] = packhl(v);
    }
  }
}

__global__ __launch_bounds__(256) void count_k(const int* __restrict__ mask,
                                               float* __restrict__ counts) {
  int s = blockIdx.x;
  int tid = threadIdx.x;
  int c = 0;
  for (int i = tid; i < HW; i += 256) c += (mask[s * HW + i] != 0);
  __shared__ int red[256];
  red[tid] = c;
  __syncthreads();
  for (int o = 128; o > 0; o >>= 1) {
    if (tid < o) red[tid] += red[tid + o];
    __syncthreads();
  }
  if (tid == 0) counts[s] = fmaxf((float)red[0], 1.0f);
}

// reads packed hi/lo fd
__global__ __launch_bounds__(256) void proto_k(const unsigned* __restrict__ fd,
                                               const int* __restrict__ mask,
                                               const float* __restrict__ counts,
                                               float* __restrict__ protos) {
  int s = blockIdx.x >> 10, c = blockIdx.x & 1023;
  int tid = threadIdx.x;
  const unsigned* row = fd + ((size_t)s * CH + c) * HW;
  const int* mrow = mask + s * HW;
  float acc = 0.f;
  for (int i = tid; i < HW; i += 256) acc += mrow[i] ? unpackhl(row[i]) : 0.f;
  __shared__ float red[256];
  red[tid] = acc;
  __syncthreads();
  for (int o = 128; o > 0; o >>= 1) {
    if (tid < o) red[tid] += red[tid + o];
    __syncthreads();
  }
  if (tid == 0) protos[blockIdx.x] = red[0] / counts[s];
}

__global__ __launch_bounds__(256) void protonorm_k(const float* __restrict__ protos,
                                                   float* __restrict__ proto) {
  int tid = threadIdx.x;
  __shared__ float sm[CH];
  __shared__ float red[256];
  float ss = 0.f;
  for (int c = tid; c < CH; c += 256) {
    float m = 0.5f * (protos[c] + protos[CH + c]);
    sm[c] = m;
    ss += m * m;
  }
  red[tid] = ss;
  __syncthreads();
  for (int o = 128; o > 0; o >>= 1) {
    if (tid < o) red[tid] += red[tid + o];
    __syncthreads();
  }
  __syncthreads();
  float inv = 1.0f / fmaxf(sqrtf(red[0]), 1e-12f);
  for (int c = tid; c < CH; c += 256) proto[c] = sm[c] * inv;
}

__global__ __launch_bounds__(256) void simfwd_k(const unsigned* __restrict__ fd,
                                                const float* __restrict__ proto,
                                                float* __restrict__ out) {
  __shared__ float p[CH];
  for (int c = threadIdx.x; c < CH; c += 256) p[c] = proto[c];
  __syncthreads();
  int n = blockIdx.x * 256 + threadIdx.x;
  const unsigned* tgt = fd + (size_t)2 * CH * HW + n;
  float s = 0.f;
  for (int c = 0; c < CH; c++) s += unpackhl(tgt[(size_t)c * HW]) * p[c];
  out[n] = s;
}

// ---------------------------------------------------------------------------
// Generic split-bf16 TN GEMM: C[m,n] = sum_k A[k*lda+m] * B[k*ldb+n], K=1024.
// A, B packed u32 = (bf16hi<<16)|bf16lo; 3 MFMA passes (hh + hl + lh).
// 128x128 tile, BK=32, 4 waves each 64x64 quadrant of 4x4 16x16x32 frags.
// LDS [m][k] u32, XOR-swizzled in 16B blocks (kb ^= m&7).
// ---------------------------------------------------------------------------
#define BM 128
#define BK 32

__global__ __launch_bounds__(256) void gemm3_tn_k(
    const unsigned* __restrict__ Ag0, int lda, size_t sA,
    const unsigned* __restrict__ Bg0, int ldb, size_t sB,
    float* __restrict__ Cg0, int ldc, size_t sC) {
  const unsigned* Ag = Ag0 + (size_t)blockIdx.z * sA;
  const unsigned* Bg = Bg0 + (size_t)blockIdx.z * sB;
  float* Cout = Cg0 + (size_t)blockIdx.z * sC;
  int m0 = blockIdx.x * BM, n0 = blockIdx.y * BM;

  __shared__ unsigned As[BM * BK];   // 16 KB
  __shared__ unsigned Bs[BM * BK];   // 16 KB

  int tid = threadIdx.x;
  int lane = tid & 63, wave = tid >> 6;
  int wr = wave >> 1, wc = wave & 1;

  int sm = tid & 127;          // staged row (m or n)
  int skh = tid >> 7;          // k-half 0/1

  int fcol = lane & 15;        // fragment m/n index
  int fkb = (lane >> 4) * 2;   // fragment kb base (16B blocks of 4 u32)

  f32x4 acc[4][4] = {};
  unsigned ra[16], rb[16];

#define LOADT(KT)                                                            \
  {                                                                          \
    const unsigned* pa = Ag + (size_t)((KT) * BK + skh * 16) * lda + m0 + sm; \
    const unsigned* pb = Bg + (size_t)((KT) * BK + skh * 16) * ldb + n0 + sm; \
    _Pragma("unroll")                                                        \
    for (int i = 0; i < 16; i++) {                                           \
      ra[i] = pa[(size_t)i * lda];                                           \
      rb[i] = pb[(size_t)i * ldb];                                           \
    }                                                                        \
  }

  LOADT(0);

  for (int kt = 0; kt < CH / BK; ++kt) {
    __syncthreads();
#pragma unroll
    for (int b = 0; b < 4; b++) {
      int kbs = ((skh * 4 + b) ^ (sm & 7)) * 4;
      u32x4 wa = {ra[b * 4 + 0], ra[b * 4 + 1], ra[b * 4 + 2], ra[b * 4 + 3]};
      u32x4 wb = {rb[b * 4 + 0], rb[b * 4 + 1], rb[b * 4 + 2], rb[b * 4 + 3]};
      *reinterpret_cast<u32x4*>(&As[sm * BK + kbs]) = wa;
      *reinterpret_cast<u32x4*>(&Bs[sm * BK + kbs]) = wb;
    }
    __syncthreads();

    if (kt + 1 < CH / BK) LOADT(kt + 1);   // prefetch hides under MFMA

    short8 bh[4], bl[4];
#pragma unroll
    for (int nf = 0; nf < 4; nf++) {
      int nloc = wc * 64 + nf * 16 + fcol;
      const unsigned* rowp = &Bs[nloc * BK];
      u32x4 p0 = *reinterpret_cast<const u32x4*>(&rowp[((fkb) ^ (nloc & 7)) * 4]);
      u32x4 p1 = *reinterpret_cast<const u32x4*>(&rowp[((fkb + 1) ^ (nloc & 7)) * 4]);
      u32x4 h, l;
      h.x = __builtin_amdgcn_perm(p0.y, p0.x, 0x07060302u);
      h.y = __builtin_amdgcn_perm(p0.w, p0.z, 0x07060302u);
      h.z = __builtin_amdgcn_perm(p1.y, p1.x, 0x07060302u);
      h.w = __builtin_amdgcn_perm(p1.w, p1.z, 0x07060302u);
      l.x = __builtin_amdgcn_perm(p0.y, p0.x, 0x05040100u);
      l.y = __builtin_amdgcn_perm(p0.w, p0.z, 0x05040100u);
      l.z = __builtin_amdgcn_perm(p1.y, p1.x, 0x05040100u);
      l.w = __builtin_amdgcn_perm(p1.w, p1.z, 0x05040100u);
      bh[nf] = __builtin_bit_cast(short8, h);
      bl[nf] = __builtin_bit_cast(short8, l);
    }
#pragma unroll
    for (int mf = 0; mf < 4; mf++) {
      int mloc = wr * 64 + mf * 16 + fcol;
      const unsigned* rowp = &As[mloc * BK];
      u32x4 p0 = *reinterpret_cast<const u32x4*>(&rowp[((fkb) ^ (mloc & 7)) * 4]);
      u32x4 p1 = *reinterpret_cast<const u32x4*>(&rowp[((fkb + 1) ^ (mloc & 7)) * 4]);
      u32x4 h, l;
      h.x = __builtin_amdgcn_perm(p0.y, p0.x, 0x07060302u);
      h.y = __builtin_amdgcn_perm(p0.w, p0.z, 0x07060302u);
      h.z = __builtin_amdgcn_perm(p1.y, p1.x, 0x07060302u);
      h.w = __builtin_amdgcn_perm(p1.w, p1.z, 0x07060302u);
      l.x = __builtin_amdgcn_perm(p0.y, p0.x, 0x05040100u);
      l.y = __builtin_amdgcn_perm(p0.w, p0.z, 0x05040100u);
      l.z = __builtin_amdgcn_perm(p1.y, p1.x, 0x05040100u);
      l.w = __builtin_amdgcn_perm(p1.w, p1.z, 0x05040100u);
      short8 ah = __builtin_bit_cast(short8, h);
      short8 al = __builtin_bit_cast(short8, l);
#pragma unroll
      for (int nf = 0; nf < 4; nf++) {
        acc[mf][nf] = __builtin_amdgcn_mfma_f32_16x16x32_bf16(ah, bh[nf], acc[mf][nf], 0, 0, 0);
        acc[mf][nf] = __builtin_amdgcn_mfma_f32_16x16x32_bf16(ah, bl[nf], acc[mf][nf], 0, 0, 0);
        acc[mf][nf] = __builtin_amdgcn_mfma_f32_16x16x32_bf16(al, bh[nf], acc[mf][nf], 0, 0, 0);
      }
    }
  }
#undef LOADT

  int rbase = (lane >> 4) * 4;
#pragma unroll
  for (int mf = 0; mf < 4; mf++) {
    int m = m0 + wr * 64 + mf * 16 + rbase;
#pragma unroll
    for (int nf = 0; nf < 4; nf++) {
      int n = n0 + wc * 64 + nf * 16 + fcol;
#pragma unroll
      for (int r = 0; r < 4; r++) {
        Cout[(size_t)(m + r) * ldc + n] = acc[mf][nf][r];
      }
    }
  }
}

// Partial argmax over hw chunks of 1024; first-occurrence tie-break.
__global__ __launch_bounds__(256) void argmax_part_k(const float* __restrict__ sim,
                                                     float* __restrict__ pmax,
                                                     int* __restrict__ pidx) {
  int s = blockIdx.z, hwc = blockIdx.y, xy0 = blockIdx.x * 64;
  int tid = threadIdx.x, xl = tid & 63, r = tid >> 6;
  const float* base = sim + ((size_t)s * HW + hwc * 1024) * HW + xy0 + xl;
  float bv = -FLT_MAX;
  int bi = 0x7fffffff;
  for (int t = 0; t < 256; t++) {
    int hw = r + 4 * t;
    float v = base[(size_t)hw * HW];
    if (v > bv) { bv = v; bi = hwc * 1024 + hw; }
  }
  __shared__ float sv[256];
  __shared__ int si[256];
  sv[tid] = bv;
  si[tid] = bi;
  __syncthreads();
  if (r == 0) {
    for (int rr = 1; rr < 4; rr++) {
      float v = sv[tid + 64 * rr];
      int i = si[tid + 64 * rr];
      if (v > bv || (v == bv && i < bi)) { bv = v; bi = i; }
    }
    int o = (s * 4 + hwc) * HW + xy0 + xl;
    pmax[o] = bv;
    pidx[o] = bi;
  }
}

__global__ __launch_bounds__(256) void votes_k(const float* __restrict__ pmax,
                                               const int* __restrict__ pidx,
                                               const int* __restrict__ mask,
                                               float* __restrict__ out) {
  int xy = blockIdx.x * 256 + threadIdx.x;
  int vote = 0;
  for (int s = 0; s < SREF; s++) {
    float bv = -FLT_MAX;
    int bi = 0x7fffffff;
    for (int hwc = 0; hwc < 4; hwc++) {
      int o = (s * 4 + hwc) * HW + xy;
      float v = pmax[o];
      int i = pidx[o];
      if (v > bv || (v == bv && i < bi)) { bv = v; bi = i; }
    }
    vote += (mask[s * HW + bi] != 0);
  }
  out[xy] = (float)vote;
}

extern "C" void kernel_launch(void* const* d_in, const int* in_sizes, int n_in,
                              void* d_out, int out_size, void* d_ws, size_t ws_size,
                              hipStream_t stream) {
  const float* fmaps = (const float*)d_in[0];
  const int* mask = (const int*)d_in[1];
  const float* basis = (const float*)d_in[2];
  float* out = (float*)d_out;
  float* ws = (float*)d_ws;

  unsigned* fnp = (unsigned*)ws;          // packed hi/lo
  float* invn = ws + 12582912;
  float* counts = ws + 12595200;
  float* protos = ws + 12595264;
  float* proto = ws + 12597312;
  float* pmax = ws + 12598336;
  int* pidx = (int*)(ws + 12631104);

  float* sim = out;
  float* simfwd = out + 33554432;
  float* votes = out + 33558528;
  float* fd_pre = out;                    // scratch in sim region (dead before sim GEMM)
  unsigned* Pp = (unsigned*)(out + 16777216);  // also scratch in sim region

  // 1) fn = l2norm(fmaps, axis=C), packed hi/lo
  colnorm_k<<<dim3(TFR * HW / 64), 256, 0, stream>>>(fmaps, invn);
  scale_pack_k<<<dim3(TFR * CH * HW / 1024), 256, 0, stream>>>(fmaps, invn, fnp);

  // 2) P = I - basis @ basis^T (packed)
  proj_pack_k<<<dim3(16, 16), 256, 0, stream>>>(basis, Pp);

  // 3) fd_pre = P @ fn  (split-bf16 MFMA), then renormalize + repack
  gemm3_tn_k<<<dim3(CH / BM, HW / BM, TFR), 256, 0, stream>>>(
      Pp, CH, 0, fnp, HW, (size_t)CH * HW, fd_pre, HW, (size_t)CH * HW);
  colnorm_k<<<dim3(TFR * HW / 64), 256, 0, stream>>>(fd_pre, invn);
  scale_pack_k<<<dim3(TFR * CH * HW / 1024), 256, 0, stream>>>(fd_pre, invn, fnp);

  // 4) prototype (packed reads)
  count_k<<<2, 256, 0, stream>>>(mask, counts);
  proto_k<<<2048, 256, 0, stream>>>(fnp, mask, counts, protos);
  protonorm_k<<<1, 256, 0, stream>>>(protos, proto);

  // 5) sim_fwd
  simfwd_k<<<16, 256, 0, stream>>>(fnp, proto, simfwd);

  // 6) sim = fd_refs^T @ fd_tgt (split-bf16 MFMA)
  gemm3_tn_k<<<dim3(HW / BM, HW / BM, SREF), 256, 0, stream>>>(
      fnp, HW, (size_t)CH * HW, fnp + (size_t)2 * CH * HW, HW, 0, sim, HW,
      (size_t)HW * HW);

  // 7) votes
  argmax_part_k<<<dim3(64, 4, 2), 256, 0, stream>>>(sim, pmax, pidx);
  votes_k<<<16, 256, 0, stream>>>(pmax, pidx, mask, votes);
}